// Round 7
// baseline (364.417 us; speedup 1.0000x reference)
//
#include <hip/hip_runtime.h>

// Attention_6219112645023 — fp32 in / fp32 out, bf16 internal compute (MFMA).
// B=2, T=2048, DIM=2048, NH=32, NKV=8, HD=64. Causal GQA + RoPE + projections.
// Pipeline: cvt5 -> qkv_gemm -> transpose(V) -> flash attn -> O gemm.
// R8/R9: attn — swapped QK^T + slot permutation + reg pipeline + setprio.
// R11/R13: GEMM 128x128/BK=64 DBUF, XOR swizzle (conflicts=0), counted vmcnt.
// R13 post-mortem: LDS port was the binding resource (~2050 cyc/tile-pair vs
// MFMA 1240); counted-vmcnt alone ~neutral.
// R14: B operand moved OFF LDS — loaded global->register directly (the MFMA
// B-frag is 16 contiguous bytes/lane), double-buffered in regs (bA/bB role
// swap, unroll-by-2), issued one full tile ahead. LDS traffic halved:
// only A staged (glds + swizzle). vmcnt(4) drains A(t)+B(t), keeps A(t+1)
// flying; B(t+1) issued after. LDS floor drops below MFMA floor.

typedef unsigned short u16;
typedef __attribute__((ext_vector_type(8))) short bf16x8;  // 8 bf16 in 4 VGPRs
typedef __attribute__((ext_vector_type(4))) float f32x4;
typedef __attribute__((ext_vector_type(4))) unsigned short u16x4;

constexpr int T_SEQ = 2048;
constexpr int DIMC  = 2048;
constexpr int NHEAD = 32;
constexpr int HDIM  = 64;
constexpr int KVDIM = 512;   // NKV * HDIM
constexpr int BATCH = 2;

__device__ __forceinline__ u16 f2bf(float f) {
    union { float f; unsigned int i; } v; v.f = f;
    unsigned int r = v.i + 0x7FFFu + ((v.i >> 16) & 1u);   // RNE
    return (u16)(r >> 16);
}

// pack two f32 -> (bf16 lo = e0, bf16 hi = e1), truncating (P in [0,1]).
__device__ __forceinline__ unsigned int pack2_bf16(float e0, float e1) {
    return __builtin_amdgcn_perm(__float_as_uint(e1), __float_as_uint(e0),
                                 0x07060302u);
}

typedef __attribute__((address_space(1))) unsigned int as1_uint;
typedef __attribute__((address_space(3))) unsigned int as3_uint;
__device__ __forceinline__ void glds16(const u16* g, u16* l) {
    // async global->LDS, 16B/lane; LDS dest = wave-uniform base + lane*16
    __builtin_amdgcn_global_load_lds((as1_uint*)(u16*)g, (as3_uint*)l, 16, 0, 0);
}

// ===========================================================================
// Fused fp32->bf16 convert of all 5 inputs (one launch).
// ===========================================================================
__global__ __launch_bounds__(256) void cvt5(const float* __restrict__ x,
                                            const float* __restrict__ wq,
                                            const float* __restrict__ wk,
                                            const float* __restrict__ wv,
                                            const float* __restrict__ wo,
                                            u16* __restrict__ xb,  u16* __restrict__ wqb,
                                            u16* __restrict__ wkb, u16* __restrict__ wvb,
                                            u16* __restrict__ wob) {
    constexpr int E0 = BATCH * T_SEQ * DIMC;          // 8388608
    constexpr int E1 = E0 + DIMC * DIMC;              // +4194304
    constexpr int E2 = E1 + KVDIM * DIMC;             // +1048576
    constexpr int E3 = E2 + KVDIM * DIMC;             // +1048576
    constexpr int E4 = E3 + DIMC * DIMC;              // 18874368 total
    for (int i = (blockIdx.x * 256 + threadIdx.x) * 4; i < E4; i += gridDim.x * 1024) {
        const float* s; u16* d; int off;
        if (i < E0)      { s = x;  d = xb;  off = 0;  }
        else if (i < E1) { s = wq; d = wqb; off = E0; }
        else if (i < E2) { s = wk; d = wkb; off = E1; }
        else if (i < E3) { s = wv; d = wvb; off = E2; }
        else             { s = wo; d = wob; off = E3; }
        f32x4 v = *(const f32x4*)(s + (i - off));
        u16x4 o;
        #pragma unroll
        for (int e = 0; e < 4; ++e) o[e] = f2bf(v[e]);
        *(u16x4*)(d + (i - off)) = o;
    }
}

// ===========================================================================
// DBUF GEMM core, R14: C = A[M][K] . W[N][K]^T, 128x128 tile, BK=64,
// 256 threads (4 waves 2x2; per-wave 64x64 = acc[4][4]).
// A: LDS-staged via glds, XOR swizzle (conflicts=0), double-buffered (32 KiB).
// B: global->REGISTER direct (no LDS). Frag (n,q2) = 16B/lane at
//    W[(colBase+wn+n*16+ln)*K + kk + q2*32 + quad*8]; double-buffered in
//    regs with unroll-by-2 role swap (all indices compile-time).
// Per tile: s_barrier (A buf free) -> issue 4 A-glds(t+1) -> vmcnt(4)
// [A(t),B(t) done; A(t+1) flying] -> issue 8 B-loads(t+1) -> s_barrier
// (A(t) published) -> ds_read A + 32 MFMA.
// ===========================================================================
template <bool OUTF32>
__device__ __forceinline__ void dgemm_core(const u16* __restrict__ A,
                                           const u16* __restrict__ W,
                                           void* __restrict__ Cv,
                                           int rowBase, int colBase,
                                           int N, int K, bool rope) {
    __shared__ __align__(16) u16 Ash[2][128 * 64];   // 32 KiB total

    const int tid  = threadIdx.x;
    const int lane = tid & 63;
    const int w    = tid >> 6;           // 0..3
    const int quad = lane >> 4;
    const int ln   = lane & 15;
    const int wm   = (w >> 1) * 64;
    const int wn   = (w & 1) * 64;

    // A staging: round r covers rows 32r + w*8 + (L>>3); global col
    // pre-swizzled 8*((L&7)^(L>>3)) (inverse of the linear LDS slot).
    const int sr = lane >> 3;
    const int sc = 8 * ((lane & 7) ^ sr);
    const u16* aS = A + (size_t)(rowBase + w * 8 + sr) * K + sc;

    // B direct: lane base for frag (n,q2) = bP + n*16*K + kk + q2*32
    const u16* bP = W + (size_t)(colBase + wn + ln) * K + quad * 8;

    f32x4 acc[4][4] = {};
    const int NT = K / 64;
    const int swz = (ln & 7) * 8;

    // prologue: A tile0 glds (4), then B tile0 loads (8)
    #pragma unroll
    for (int r = 0; r < 4; ++r)
        glds16(aS + (size_t)(r * 32) * K, &Ash[0][(w + 4 * r) * 512]);
    bf16x8 bA[8], bB[8];
    #pragma unroll
    for (int n = 0; n < 4; ++n) {
        bA[2 * n]     = *(const bf16x8*)(bP + (size_t)(n * 16) * K);
        bA[2 * n + 1] = *(const bf16x8*)(bP + (size_t)(n * 16) * K + 32);
    }

    auto tile_step = [&](int t, u16* Abuf, u16* Anext, bf16x8* bc, bf16x8* bn) {
        __builtin_amdgcn_s_barrier();            // all reads of Anext retired
        __builtin_amdgcn_sched_barrier(0);
        if (t + 1 < NT) {
            const size_t ko = (size_t)(t + 1) * 64;
            #pragma unroll
            for (int r = 0; r < 4; ++r)
                glds16(aS + ko + (size_t)(r * 32) * K, Anext + (w + 4 * r) * 512);
            __builtin_amdgcn_sched_barrier(0);
            // order: [A(t)4, B(t)8, A(t+1)4] -> leave 4: A(t),B(t) drained
            __asm__ __volatile__("s_waitcnt vmcnt(4)" ::: "memory");
            __builtin_amdgcn_sched_barrier(0);
            #pragma unroll
            for (int n = 0; n < 4; ++n) {
                bn[2 * n]     = *(const bf16x8*)(bP + (size_t)(n * 16) * K + ko);
                bn[2 * n + 1] = *(const bf16x8*)(bP + (size_t)(n * 16) * K + ko + 32);
            }
            __builtin_amdgcn_sched_barrier(0);
        } else {
            __asm__ __volatile__("s_waitcnt vmcnt(0)" ::: "memory");
            __builtin_amdgcn_sched_barrier(0);
        }
        __builtin_amdgcn_s_barrier();            // A tile t published
        #pragma unroll
        for (int q2 = 0; q2 < 2; ++q2) {
            __builtin_amdgcn_s_setprio(1);
            #pragma unroll
            for (int m = 0; m < 4; ++m) {
                bf16x8 af = *(const bf16x8*)(Abuf + (wm + m * 16 + ln) * 64
                                                  + ((q2 * 32 + quad * 8) ^ swz));
                #pragma unroll
                for (int n = 0; n < 4; ++n)
                    acc[m][n] = __builtin_amdgcn_mfma_f32_16x16x32_bf16(
                                    af, bc[2 * n + q2], acc[m][n], 0, 0, 0);
            }
            __builtin_amdgcn_s_setprio(0);
        }
    };

    for (int t = 0; t < NT; t += 2) {            // NT even (K % 128 == 0)
        tile_step(t,     &Ash[0][0], &Ash[1][0], bA, bB);
        tile_step(t + 1, &Ash[1][0], &Ash[0][0], bB, bA);
    }

    if (rope) {
        // head-local d = j*16+ln; pairs (d, d+32) -> (acc[i][j], acc[i][j+2]).
        #pragma unroll
        for (int j = 0; j < 2; ++j) {
            const int d = j * 16 + ln;
            const float invrev = exp2f(-(float)d * (13.287712379549449f / 32.0f))
                                 * 0.15915494309189535f;   // /2pi
            #pragma unroll
            for (int i = 0; i < 4; ++i) {
                #pragma unroll
                for (int r = 0; r < 4; ++r) {
                    const int t = (rowBase + wm + i * 16 + quad * 4 + r) & (T_SEQ - 1);
                    float rev = (float)t * invrev;
                    float fr = rev - floorf(rev);
                    float sn = __builtin_amdgcn_sinf(fr);
                    float cs = __builtin_amdgcn_cosf(fr);
                    float a0 = acc[i][j][r], a2 = acc[i][j + 2][r];
                    acc[i][j][r]     = a0 * cs - a2 * sn;
                    acc[i][j + 2][r] = a2 * cs + a0 * sn;
                }
            }
        }
    }

    #pragma unroll
    for (int i = 0; i < 4; ++i) {
        int mrow = rowBase + wm + i * 16 + quad * 4;
        #pragma unroll
        for (int j = 0; j < 4; ++j) {
            int n = colBase + wn + j * 16 + ln;
            #pragma unroll
            for (int r = 0; r < 4; ++r) {
                if constexpr (OUTF32)
                    ((float*)Cv)[(size_t)(mrow + r) * N + n] = acc[i][j][r];
                else
                    ((u16*)Cv)[(size_t)(mrow + r) * N + n] = f2bf(acc[i][j][r]);
            }
        }
    }
}

// Fused QKV: 24 col-tiles (Q 16 | K 4 | V 4) x 32 row-tiles = 768 blocks.
// Bijective XCD swizzle (768 % 8 == 0); consecutive nf share the A row-panel.
__global__ __launch_bounds__(256, 2) void qkv_gemm(const u16* __restrict__ xb,
                                                   const u16* __restrict__ wqb,
                                                   const u16* __restrict__ wkb,
                                                   const u16* __restrict__ wvb,
                                                   u16* __restrict__ Qb,
                                                   u16* __restrict__ Kb,
                                                   u16* __restrict__ Vb) {
    const int flat = blockIdx.y * 24 + blockIdx.x;
    const int nf   = (flat & 7) * 96 + (flat >> 3);
    const int ct   = nf % 24;
    const int rowBase = (nf / 24) * 128;

    const u16* W; u16* C; int colBase, N; bool rope;
    if (ct < 16)      { W = wqb; C = Qb; colBase = ct * 128;        N = DIMC;  rope = true; }
    else if (ct < 20) { W = wkb; C = Kb; colBase = (ct - 16) * 128; N = KVDIM; rope = true; }
    else              { W = wvb; C = Vb; colBase = (ct - 20) * 128; N = KVDIM; rope = false; }
    dgemm_core<false>(xb, W, C, rowBase, colBase, N, DIMC, rope);
}

// O-projection: 16 col-tiles x 32 row-tiles = 512 blocks, XCD-swizzled.
__global__ __launch_bounds__(256, 2) void gemm_out(const u16* __restrict__ A,
                                                   const u16* __restrict__ W,
                                                   float* __restrict__ C) {
    const int flat = blockIdx.y * 16 + blockIdx.x;
    const int nf   = (flat & 7) * 64 + (flat >> 3);
    const int colBase = (nf % 16) * 128;
    const int rowBase = (nf / 16) * 128;
    dgemm_core<true>(A, W, C, rowBase, colBase, DIMC, DIMC, false);
}

// ===========================================================================
// V [B*T][KVDIM] -> Vt [B][KVDIM][T]
// ===========================================================================
__global__ __launch_bounds__(256) void transpose_v(const u16* __restrict__ V,
                                                   u16* __restrict__ Vt) {
    __shared__ __align__(16) u16 tile[32][33];
    const int x = threadIdx.x & 31;
    const int y = threadIdx.x >> 5;
    const int tok0 = blockIdx.y * 32;
    const int c0   = blockIdx.x * 32;
    #pragma unroll
    for (int yy = 0; yy < 32; yy += 8)
        tile[y + yy][x] = V[(size_t)(tok0 + y + yy) * KVDIM + c0 + x];
    __syncthreads();
    const int b  = tok0 >> 11;
    const int t0 = tok0 & (T_SEQ - 1);
    #pragma unroll
    for (int yy = 0; yy < 32; yy += 8)
        Vt[(size_t)(b * KVDIM + c0 + y + yy) * T_SEQ + t0 + x] = tile[x][y + yy];
}

// ===========================================================================
// Flash attention. grid = (16, NH, B), block = 256 (4 waves).
// R8: swapped QK^T (D[key][q]) + key->slot permutation
//   slot(k) = 32*(k>>5) + 8*((k>>2)&3) + 4*((k>>4)&1) + (k&3)
// R9: T14 async-STAGE reg pipeline + T5 setprio.
// R13: K/V double-buffered (36 KB) -> ONE raw barrier per kt.
// ===========================================================================
__global__ __launch_bounds__(256) void attn(const u16* __restrict__ Q,
                                            const u16* __restrict__ Kx,
                                            const u16* __restrict__ Vt,
                                            u16* __restrict__ O) {
    __shared__ __align__(16) u16 Ks[2][64][72];    // [buf][key][dim]
    __shared__ __align__(16) u16 Vs[2][64][72];    // [buf][dim][slot]

    const int tid  = threadIdx.x;
    const int lane = tid & 63;
    const int w    = tid >> 6;
    const int quad = lane >> 4;
    const int ln   = lane & 15;
    const int h    = blockIdx.y;
    const int b    = blockIdx.z;
    const int kvh  = h >> 2;

    const int srow = tid >> 2;           // 0..63
    const int c    = tid & 3;
    const int scol = c * 16;             // token group base (16 tokens)
    const int vsb  = 32 * (c >> 1) + 4 * (c & 1);
    const u16* kbase = Kx + (size_t)(b * T_SEQ + srow) * KVDIM + kvh * HDIM + scol;
    const u16* vbase = Vt + (size_t)(b * KVDIM + kvh * HDIM + srow) * T_SEQ;

    const float K1 = 0.125f * 1.4426950408889634f;   // scale * log2(e)
    const float K2 = 8.0f * 1.4426950408889634f;     // M0 * log2(e)

    #pragma unroll
    for (int phase = 0; phase < 2; ++phase) {
        const int qt = phase ? (31 - (int)blockIdx.x) : (int)blockIdx.x;
        const int qr0 = qt * 64 + w * 16;

        const u16* qp = Q + (size_t)(b * T_SEQ + qr0 + ln) * DIMC + h * HDIM + quad * 8;
        const bf16x8 bq0 = *(const bf16x8*)qp;        // B-operand: col = q = ln
        const bf16x8 bq1 = *(const bf16x8*)(qp + 32);

        f32x4 o[4] = {};
        float lsum = 0.0f;

        // pipeline prologue: tile-0 staging loads into registers
        bf16x8 kra = *(const bf16x8*)kbase;
        bf16x8 krb = *(const bf16x8*)(kbase + 8);
        bf16x8 vra = *(const bf16x8*)(vbase + scol);
        bf16x8 vrb = *(const bf16x8*)(vbase + scol + 8);

        for (int kt = 0; kt <= qt; ++kt) {
            const int cb = kt & 1;

            *(bf16x8*)&Ks[cb][srow][scol]     = kra;
            *(bf16x8*)&Ks[cb][srow][scol + 8] = krb;
            {   // V staging, slot-permuted: 4x ds_write_b64
                union { bf16x8 v; u16x4 h4[2]; } ua, ub;
                ua.v = vra; ub.v = vrb;
                *(u16x4*)&Vs[cb][srow][vsb]      = ua.h4[0];
                *(u16x4*)&Vs[cb][srow][vsb + 8]  = ua.h4[1];
                *(u16x4*)&Vs[cb][srow][vsb + 16] = ub.h4[0];
                *(u16x4*)&Vs[cb][srow][vsb + 24] = ub.h4[1];
            }

            // prefetch tile kt+1 into regs — flies under this tile's compute
            if (kt < qt) {
                const size_t ko = (size_t)(kt + 1) * 64;
                kra = *(const bf16x8*)(kbase + ko * KVDIM);
                krb = *(const bf16x8*)(kbase + ko * KVDIM + 8);
                vra = *(const bf16x8*)(vbase + ko + scol);
                vrb = *(const bf16x8*)(vbase + ko + scol + 8);
            }

            // own LDS writes (and prior reads) drained, then ONE raw barrier
            __asm__ __volatile__("s_waitcnt lgkmcnt(0)" ::: "memory");
            __builtin_amdgcn_s_barrier();

            f32x4 s[4];
            __builtin_amdgcn_s_setprio(1);
            #pragma unroll
            for (int st = 0; st < 4; ++st) {
                f32x4 z = {};
                s[st] = __builtin_amdgcn_mfma_f32_16x16x32_bf16(
                            *(const bf16x8*)&Ks[cb][st * 16 + ln][quad * 8], bq0, z, 0, 0, 0);
                s[st] = __builtin_amdgcn_mfma_f32_16x16x32_bf16(
                            *(const bf16x8*)&Ks[cb][st * 16 + ln][32 + quad * 8], bq1, s[st], 0, 0, 0);
            }
            __builtin_amdgcn_s_setprio(0);

            unsigned int pk[8];
            if (kt != qt) {
                #pragma unroll
                for (int st = 0; st < 4; ++st) {
                    float e0 = exp2f(fmaf(s[st][0], K1, -K2));
                    float e1 = exp2f(fmaf(s[st][1], K1, -K2));
                    float e2 = exp2f(fmaf(s[st][2], K1, -K2));
                    float e3 = exp2f(fmaf(s[st][3], K1, -K2));
                    lsum += (e0 + e1) + (e2 + e3);
                    pk[2 * st]     = pack2_bf16(e0, e1);
                    pk[2 * st + 1] = pack2_bf16(e2, e3);
                }
            } else {
                const int thr = w * 16 + ln;            // q local in 64-block
                #pragma unroll
                for (int st = 0; st < 4; ++st) {
                    float e[4];
                    #pragma unroll
                    for (int r = 0; r < 4; ++r) {
                        const int key = st * 16 + quad * 4 + r;
                        e[r] = (key > thr) ? 0.0f : exp2f(fmaf(s[st][r], K1, -K2));
                    }
                    lsum += (e[0] + e[1]) + (e[2] + e[3]);
                    pk[2 * st]     = pack2_bf16(e[0], e[1]);
                    pk[2 * st + 1] = pack2_bf16(e[2], e[3]);
                }
            }

            union { unsigned int u[4]; bf16x8 v; } a0, a1;
            a0.u[0] = pk[0]; a0.u[1] = pk[1]; a0.u[2] = pk[2]; a0.u[3] = pk[3];
            a1.u[0] = pk[4]; a1.u[1] = pk[5]; a1.u[2] = pk[6]; a1.u[3] = pk[7];

            __builtin_amdgcn_s_setprio(1);
            #pragma unroll
            for (int t = 0; t < 4; ++t) {
                o[t] = __builtin_amdgcn_mfma_f32_16x16x32_bf16(
                           a0.v, *(const bf16x8*)&Vs[cb][t * 16 + ln][quad * 8], o[t], 0, 0, 0);
                o[t] = __builtin_amdgcn_mfma_f32_16x16x32_bf16(
                           a1.v, *(const bf16x8*)&Vs[cb][t * 16 + ln][32 + quad * 8], o[t], 0, 0, 0);
            }
            __builtin_amdgcn_s_setprio(0);
        }

        float ls = lsum;
        ls += __shfl_xor(ls, 16);
        ls += __shfl_xor(ls, 32);
        #pragma unroll
        for (int r = 0; r < 4; ++r) {
            const float inv = 1.0f / __shfl(ls, quad * 4 + r);
            size_t obase = (size_t)(b * T_SEQ + qr0 + quad * 4 + r) * DIMC + h * HDIM;
            #pragma unroll
            for (int t = 0; t < 4; ++t)
                O[obase + t * 16 + ln] = f2bf(o[t][r] * inv);
        }

        // phase boundary: next phase's first ds_writes must not race
        // this phase's last ds_reads on slow waves.
        __syncthreads();
    }
}

// ===========================================================================
extern "C" void kernel_launch(void* const* d_in, const int* in_sizes, int n_in,
                              void* d_out, int out_size, void* d_ws, size_t ws_size,
                              hipStream_t stream) {
    const float* x  = (const float*)d_in[0];
    const float* wq = (const float*)d_in[1];
    const float* wk = (const float*)d_in[2];
    const float* wv = (const float*)d_in[3];
    const float* wo = (const float*)d_in[4];
    float* out = (float*)d_out;

    char* ws = (char*)d_ws;
    constexpr size_t MB = 1024 * 1024;
    u16* Qb  = (u16*)(ws);             // 16 MB [4096][2048]
    u16* Kb  = (u16*)(ws + 16 * MB);   //  4 MB [4096][512]
    u16* Vb  = (u16*)(ws + 20 * MB);   //  4 MB [4096][512]
    u16* Vtb = (u16*)(ws + 24 * MB);   //  4 MB [2][512][2048]
    u16* AOb = (u16*)(ws + 28 * MB);   // 16 MB [4096][2048]  (aliases xb)
    u16* xb  = AOb;                    // x dead before attn writes AOb
    u16* wqb = (u16*)(ws + 44 * MB);   //  8 MB
    u16* wkb = (u16*)(ws + 52 * MB);   //  2 MB
    u16* wvb = (u16*)(ws + 54 * MB);   //  2 MB
    u16* wob = (u16*)(ws + 56 * MB);   //  8 MB
    const int M = BATCH * T_SEQ;       // 4096

    hipLaunchKernelGGL(cvt5, dim3(2048), dim3(256), 0, stream,
                       x, wq, wk, wv, wo, xb, wqb, wkb, wvb, wob);
    hipLaunchKernelGGL(qkv_gemm, dim3(24, M / 128), dim3(256), 0, stream,
                       xb, wqb, wkb, wvb, Qb, Kb, Vb);
    hipLaunchKernelGGL(transpose_v, dim3(KVDIM / 32, M / 32), dim3(256), 0, stream, Vb, Vtb);
    hipLaunchKernelGGL(attn, dim3(16, NHEAD, BATCH), dim3(256), 0, stream,
                       Qb, Kb, Vtb, AOb);
    hipLaunchKernelGGL(gemm_out, dim3(DIMC / 128, M / 128), dim3(256), 0, stream,
                       AOb, wob, out);
}

// Round 8
// 309.935 us; speedup vs baseline: 1.1758x; 1.1758x over previous
//
#include <hip/hip_runtime.h>

// Attention_6219112645023 — fp32 in / fp32 out, bf16 internal compute (MFMA).
// B=2, T=2048, DIM=2048, NH=32, NKV=8, HD=64. Causal GQA + RoPE + projections.
// Pipeline: cvt5 -> qkv_gemm -> transpose(V) -> flash attn -> O gemm.
// R8/R9: attn — swapped QK^T + slot permutation + reg pipeline + setprio.
// R11: GEMM 128x128/BK=64 4-wave DBUF, XOR swizzle (conflicts=0).
// R13: counted vmcnt (never drain in loop); attn K/V dbuf, 1 barrier/kt.
// R14 lesson: B global->reg direct = 64B-segment L2 thrash, -36%. REVERTED.
// R15: split the 8 prefetch glds across the two q2 compute halves (4 at tile
// top -> vmcnt(4) drains t with 4 of t+1 flying; 4 issued mid-tile between
// q2=0 and q2=1). Spreads VMEM issue away from the post-barrier ds_read
// burst (m196 mechanism: interleave staging INSIDE compute phases).

typedef unsigned short u16;
typedef __attribute__((ext_vector_type(8))) short bf16x8;  // 8 bf16 in 4 VGPRs
typedef __attribute__((ext_vector_type(4))) float f32x4;
typedef __attribute__((ext_vector_type(4))) unsigned short u16x4;

constexpr int T_SEQ = 2048;
constexpr int DIMC  = 2048;
constexpr int NHEAD = 32;
constexpr int HDIM  = 64;
constexpr int KVDIM = 512;   // NKV * HDIM
constexpr int BATCH = 2;

__device__ __forceinline__ u16 f2bf(float f) {
    union { float f; unsigned int i; } v; v.f = f;
    unsigned int r = v.i + 0x7FFFu + ((v.i >> 16) & 1u);   // RNE
    return (u16)(r >> 16);
}

// pack two f32 -> (bf16 lo = e0, bf16 hi = e1), truncating (P in [0,1]).
__device__ __forceinline__ unsigned int pack2_bf16(float e0, float e1) {
    return __builtin_amdgcn_perm(__float_as_uint(e1), __float_as_uint(e0),
                                 0x07060302u);
}

typedef __attribute__((address_space(1))) unsigned int as1_uint;
typedef __attribute__((address_space(3))) unsigned int as3_uint;
__device__ __forceinline__ void glds16(const u16* g, u16* l) {
    // async global->LDS, 16B/lane; LDS dest = wave-uniform base + lane*16
    __builtin_amdgcn_global_load_lds((as1_uint*)(u16*)g, (as3_uint*)l, 16, 0, 0);
}

// ===========================================================================
// Fused fp32->bf16 convert of all 5 inputs (one launch).
// ===========================================================================
__global__ __launch_bounds__(256) void cvt5(const float* __restrict__ x,
                                            const float* __restrict__ wq,
                                            const float* __restrict__ wk,
                                            const float* __restrict__ wv,
                                            const float* __restrict__ wo,
                                            u16* __restrict__ xb,  u16* __restrict__ wqb,
                                            u16* __restrict__ wkb, u16* __restrict__ wvb,
                                            u16* __restrict__ wob) {
    constexpr int E0 = BATCH * T_SEQ * DIMC;          // 8388608
    constexpr int E1 = E0 + DIMC * DIMC;              // +4194304
    constexpr int E2 = E1 + KVDIM * DIMC;             // +1048576
    constexpr int E3 = E2 + KVDIM * DIMC;             // +1048576
    constexpr int E4 = E3 + DIMC * DIMC;              // 18874368 total
    for (int i = (blockIdx.x * 256 + threadIdx.x) * 4; i < E4; i += gridDim.x * 1024) {
        const float* s; u16* d; int off;
        if (i < E0)      { s = x;  d = xb;  off = 0;  }
        else if (i < E1) { s = wq; d = wqb; off = E0; }
        else if (i < E2) { s = wk; d = wkb; off = E1; }
        else if (i < E3) { s = wv; d = wvb; off = E2; }
        else             { s = wo; d = wob; off = E3; }
        f32x4 v = *(const f32x4*)(s + (i - off));
        u16x4 o;
        #pragma unroll
        for (int e = 0; e < 4; ++e) o[e] = f2bf(v[e]);
        *(u16x4*)(d + (i - off)) = o;
    }
}

// ===========================================================================
// DBUF GEMM core: C = A[M][K] . W[N][K]^T, bf16 in, 128x128 tile, BK=64,
// 256 threads (4 waves, 2x2; per-wave 64x64 = acc[4][4]).
// LDS: 2 bufs x (A 128x64 + B 128x64) = 64 KiB.
// Swizzle (conflicts=0 proven): logical (row,col) at LDS elem
//   row*64 + (col ^ ((row&7)*8)); glds SOURCE col pre-swizzled (linear dest).
// R15 schedule per K-tile:
//   s_barrier                    // all waves done READING buf cb^1
//   issue 4 glds t+1 (half A+B)  // into cb^1
//   s_waitcnt vmcnt(4)           // t's 8 done; t+1's first 4 STAY FLYING
//   s_barrier                    // tile t published
//   q2=0: 8 ds_read + 16 MFMA
//   issue 4 glds t+1 (2nd half)  // spread VMEM issue into compute
//   q2=1: 8 ds_read + 16 MFMA
// Outstanding at each tile top = 8; never drains to 0 in the loop.
// ===========================================================================
template <bool OUTF32>
__device__ __forceinline__ void dgemm_core(const u16* __restrict__ A,
                                           const u16* __restrict__ W,
                                           void* __restrict__ Cv,
                                           int rowBase, int colBase,
                                           int N, int K, bool rope) {
    __shared__ __align__(16) u16 Ash[2][128 * 64];   // 32 KiB
    __shared__ __align__(16) u16 Bsh[2][128 * 64];   // 32 KiB

    const int tid  = threadIdx.x;
    const int lane = tid & 63;
    const int w    = tid >> 6;           // 0..3
    const int quad = lane >> 4;
    const int ln   = lane & 15;
    const int wm   = (w >> 1) * 64;
    const int wn   = (w & 1) * 64;

    // staging: round r (0..3) covers rows 32r + w*8 + (L>>3); lane L's global
    // col elems = 8*((L&7) ^ (L>>3)) (inverse-swizzle of its linear LDS slot).
    const int sr = lane >> 3;            // 0..7
    const int sc = 8 * ((lane & 7) ^ sr);
    const u16* aS = A + (size_t)(rowBase + w * 8 + sr) * K + sc;
    const u16* bS = W + (size_t)(colBase + w * 8 + sr) * K + sc;

    f32x4 acc[4][4] = {};
    const int NT = K / 64;
    const int swz = (ln & 7) * 8;

    // prologue: stage tile 0 -> buf 0 (8 glds/thread)
    #pragma unroll
    for (int r = 0; r < 4; ++r) {
        glds16(aS + (size_t)(r * 32) * K, &Ash[0][(w + 4 * r) * 512]);
        glds16(bS + (size_t)(r * 32) * K, &Bsh[0][(w + 4 * r) * 512]);
    }

    for (int t = 0; t < NT; ++t) {
        const int cb = t & 1;
        __builtin_amdgcn_s_barrier();          // reads of buf cb^1 complete
        __builtin_amdgcn_sched_barrier(0);

        const bool pf = (t + 1 < NT);
        const size_t ko = (size_t)(t + 1) * 64;
        u16* An = &Ash[cb ^ 1][0];
        u16* Bn = &Bsh[cb ^ 1][0];

        if (pf) {
            #pragma unroll
            for (int r = 0; r < 2; ++r) {      // first half of t+1
                glds16(aS + ko + (size_t)(r * 32) * K, An + (w + 4 * r) * 512);
                glds16(bS + ko + (size_t)(r * 32) * K, Bn + (w + 4 * r) * 512);
            }
            __builtin_amdgcn_sched_barrier(0);
            __asm__ __volatile__("s_waitcnt vmcnt(4)" ::: "memory");  // t done
        } else {
            __asm__ __volatile__("s_waitcnt vmcnt(0)" ::: "memory");  // drain
        }
        __builtin_amdgcn_sched_barrier(0);
        __builtin_amdgcn_s_barrier();          // tile t published

        const u16* Ap = &Ash[cb][0];
        const u16* Bp = &Bsh[cb][0];
        #pragma unroll
        for (int q2 = 0; q2 < 2; ++q2) {
            bf16x8 bwf[4];
            #pragma unroll
            for (int n = 0; n < 4; ++n)
                bwf[n] = *(const bf16x8*)(Bp + (wn + n * 16 + ln) * 64
                                             + ((q2 * 32 + quad * 8) ^ swz));
            __builtin_amdgcn_s_setprio(1);
            #pragma unroll
            for (int m = 0; m < 4; ++m) {
                bf16x8 af = *(const bf16x8*)(Ap + (wm + m * 16 + ln) * 64
                                                + ((q2 * 32 + quad * 8) ^ swz));
                #pragma unroll
                for (int n = 0; n < 4; ++n)
                    acc[m][n] = __builtin_amdgcn_mfma_f32_16x16x32_bf16(af, bwf[n], acc[m][n], 0, 0, 0);
            }
            __builtin_amdgcn_s_setprio(0);
            if (q2 == 0 && pf) {               // second half of t+1, mid-tile
                #pragma unroll
                for (int r = 2; r < 4; ++r) {
                    glds16(aS + ko + (size_t)(r * 32) * K, An + (w + 4 * r) * 512);
                    glds16(bS + ko + (size_t)(r * 32) * K, Bn + (w + 4 * r) * 512);
                }
                __builtin_amdgcn_sched_barrier(0);
            }
        }
    }

    if (rope) {
        // head-local d = j*16+ln; pairs (d, d+32) -> (acc[i][j], acc[i][j+2]).
        #pragma unroll
        for (int j = 0; j < 2; ++j) {
            const int d = j * 16 + ln;
            const float invrev = exp2f(-(float)d * (13.287712379549449f / 32.0f))
                                 * 0.15915494309189535f;   // /2pi
            #pragma unroll
            for (int i = 0; i < 4; ++i) {
                #pragma unroll
                for (int r = 0; r < 4; ++r) {
                    const int t = (rowBase + wm + i * 16 + quad * 4 + r) & (T_SEQ - 1);
                    float rev = (float)t * invrev;
                    float fr = rev - floorf(rev);
                    float sn = __builtin_amdgcn_sinf(fr);
                    float cs = __builtin_amdgcn_cosf(fr);
                    float a0 = acc[i][j][r], a2 = acc[i][j + 2][r];
                    acc[i][j][r]     = a0 * cs - a2 * sn;
                    acc[i][j + 2][r] = a2 * cs + a0 * sn;
                }
            }
        }
    }

    #pragma unroll
    for (int i = 0; i < 4; ++i) {
        int mrow = rowBase + wm + i * 16 + quad * 4;
        #pragma unroll
        for (int j = 0; j < 4; ++j) {
            int n = colBase + wn + j * 16 + ln;
            #pragma unroll
            for (int r = 0; r < 4; ++r) {
                if constexpr (OUTF32)
                    ((float*)Cv)[(size_t)(mrow + r) * N + n] = acc[i][j][r];
                else
                    ((u16*)Cv)[(size_t)(mrow + r) * N + n] = f2bf(acc[i][j][r]);
            }
        }
    }
}

// Fused QKV: 24 col-tiles (Q 16 | K 4 | V 4) x 32 row-tiles = 768 blocks.
// Bijective XCD swizzle (768 % 8 == 0); consecutive nf share the A row-panel.
__global__ __launch_bounds__(256, 2) void qkv_gemm(const u16* __restrict__ xb,
                                                   const u16* __restrict__ wqb,
                                                   const u16* __restrict__ wkb,
                                                   const u16* __restrict__ wvb,
                                                   u16* __restrict__ Qb,
                                                   u16* __restrict__ Kb,
                                                   u16* __restrict__ Vb) {
    const int flat = blockIdx.y * 24 + blockIdx.x;
    const int nf   = (flat & 7) * 96 + (flat >> 3);
    const int ct   = nf % 24;
    const int rowBase = (nf / 24) * 128;

    const u16* W; u16* C; int colBase, N; bool rope;
    if (ct < 16)      { W = wqb; C = Qb; colBase = ct * 128;        N = DIMC;  rope = true; }
    else if (ct < 20) { W = wkb; C = Kb; colBase = (ct - 16) * 128; N = KVDIM; rope = true; }
    else              { W = wvb; C = Vb; colBase = (ct - 20) * 128; N = KVDIM; rope = false; }
    dgemm_core<false>(xb, W, C, rowBase, colBase, N, DIMC, rope);
}

// O-projection: 16 col-tiles x 32 row-tiles = 512 blocks, XCD-swizzled.
__global__ __launch_bounds__(256, 2) void gemm_out(const u16* __restrict__ A,
                                                   const u16* __restrict__ W,
                                                   float* __restrict__ C) {
    const int flat = blockIdx.y * 16 + blockIdx.x;
    const int nf   = (flat & 7) * 64 + (flat >> 3);
    const int colBase = (nf % 16) * 128;
    const int rowBase = (nf / 16) * 128;
    dgemm_core<true>(A, W, C, rowBase, colBase, DIMC, DIMC, false);
}

// ===========================================================================
// V [B*T][KVDIM] -> Vt [B][KVDIM][T]
// ===========================================================================
__global__ __launch_bounds__(256) void transpose_v(const u16* __restrict__ V,
                                                   u16* __restrict__ Vt) {
    __shared__ __align__(16) u16 tile[32][33];
    const int x = threadIdx.x & 31;
    const int y = threadIdx.x >> 5;
    const int tok0 = blockIdx.y * 32;
    const int c0   = blockIdx.x * 32;
    #pragma unroll
    for (int yy = 0; yy < 32; yy += 8)
        tile[y + yy][x] = V[(size_t)(tok0 + y + yy) * KVDIM + c0 + x];
    __syncthreads();
    const int b  = tok0 >> 11;
    const int t0 = tok0 & (T_SEQ - 1);
    #pragma unroll
    for (int yy = 0; yy < 32; yy += 8)
        Vt[(size_t)(b * KVDIM + c0 + y + yy) * T_SEQ + t0 + x] = tile[x][y + yy];
}

// ===========================================================================
// Flash attention. grid = (16, NH, B), block = 256 (4 waves).
// R8: swapped QK^T (D[key][q]) + key->slot permutation
//   slot(k) = 32*(k>>5) + 8*((k>>2)&3) + 4*((k>>4)&1) + (k&3)
// R9: T14 async-STAGE reg pipeline + T5 setprio.
// R13: K/V double-buffered (36 KB) -> ONE raw barrier per kt.
// ===========================================================================
__global__ __launch_bounds__(256) void attn(const u16* __restrict__ Q,
                                            const u16* __restrict__ Kx,
                                            const u16* __restrict__ Vt,
                                            u16* __restrict__ O) {
    __shared__ __align__(16) u16 Ks[2][64][72];    // [buf][key][dim]
    __shared__ __align__(16) u16 Vs[2][64][72];    // [buf][dim][slot]

    const int tid  = threadIdx.x;
    const int lane = tid & 63;
    const int w    = tid >> 6;
    const int quad = lane >> 4;
    const int ln   = lane & 15;
    const int h    = blockIdx.y;
    const int b    = blockIdx.z;
    const int kvh  = h >> 2;

    const int srow = tid >> 2;           // 0..63
    const int c    = tid & 3;
    const int scol = c * 16;             // token group base (16 tokens)
    const int vsb  = 32 * (c >> 1) + 4 * (c & 1);
    const u16* kbase = Kx + (size_t)(b * T_SEQ + srow) * KVDIM + kvh * HDIM + scol;
    const u16* vbase = Vt + (size_t)(b * KVDIM + kvh * HDIM + srow) * T_SEQ;

    const float K1 = 0.125f * 1.4426950408889634f;   // scale * log2(e)
    const float K2 = 8.0f * 1.4426950408889634f;     // M0 * log2(e)

    #pragma unroll
    for (int phase = 0; phase < 2; ++phase) {
        const int qt = phase ? (31 - (int)blockIdx.x) : (int)blockIdx.x;
        const int qr0 = qt * 64 + w * 16;

        const u16* qp = Q + (size_t)(b * T_SEQ + qr0 + ln) * DIMC + h * HDIM + quad * 8;
        const bf16x8 bq0 = *(const bf16x8*)qp;        // B-operand: col = q = ln
        const bf16x8 bq1 = *(const bf16x8*)(qp + 32);

        f32x4 o[4] = {};
        float lsum = 0.0f;

        // pipeline prologue: tile-0 staging loads into registers
        bf16x8 kra = *(const bf16x8*)kbase;
        bf16x8 krb = *(const bf16x8*)(kbase + 8);
        bf16x8 vra = *(const bf16x8*)(vbase + scol);
        bf16x8 vrb = *(const bf16x8*)(vbase + scol + 8);

        for (int kt = 0; kt <= qt; ++kt) {
            const int cb = kt & 1;

            *(bf16x8*)&Ks[cb][srow][scol]     = kra;
            *(bf16x8*)&Ks[cb][srow][scol + 8] = krb;
            {   // V staging, slot-permuted: 4x ds_write_b64
                union { bf16x8 v; u16x4 h4[2]; } ua, ub;
                ua.v = vra; ub.v = vrb;
                *(u16x4*)&Vs[cb][srow][vsb]      = ua.h4[0];
                *(u16x4*)&Vs[cb][srow][vsb + 8]  = ua.h4[1];
                *(u16x4*)&Vs[cb][srow][vsb + 16] = ub.h4[0];
                *(u16x4*)&Vs[cb][srow][vsb + 24] = ub.h4[1];
            }

            // prefetch tile kt+1 into regs — flies under this tile's compute
            if (kt < qt) {
                const size_t ko = (size_t)(kt + 1) * 64;
                kra = *(const bf16x8*)(kbase + ko * KVDIM);
                krb = *(const bf16x8*)(kbase + ko * KVDIM + 8);
                vra = *(const bf16x8*)(vbase + ko + scol);
                vrb = *(const bf16x8*)(vbase + ko + scol + 8);
            }

            // own LDS writes (and prior reads) drained, then ONE raw barrier
            __asm__ __volatile__("s_waitcnt lgkmcnt(0)" ::: "memory");
            __builtin_amdgcn_s_barrier();

            f32x4 s[4];
            __builtin_amdgcn_s_setprio(1);
            #pragma unroll
            for (int st = 0; st < 4; ++st) {
                f32x4 z = {};
                s[st] = __builtin_amdgcn_mfma_f32_16x16x32_bf16(
                            *(const bf16x8*)&Ks[cb][st * 16 + ln][quad * 8], bq0, z, 0, 0, 0);
                s[st] = __builtin_amdgcn_mfma_f32_16x16x32_bf16(
                            *(const bf16x8*)&Ks[cb][st * 16 + ln][32 + quad * 8], bq1, s[st], 0, 0, 0);
            }
            __builtin_amdgcn_s_setprio(0);

            unsigned int pk[8];
            if (kt != qt) {
                #pragma unroll
                for (int st = 0; st < 4; ++st) {
                    float e0 = exp2f(fmaf(s[st][0], K1, -K2));
                    float e1 = exp2f(fmaf(s[st][1], K1, -K2));
                    float e2 = exp2f(fmaf(s[st][2], K1, -K2));
                    float e3 = exp2f(fmaf(s[st][3], K1, -K2));
                    lsum += (e0 + e1) + (e2 + e3);
                    pk[2 * st]     = pack2_bf16(e0, e1);
                    pk[2 * st + 1] = pack2_bf16(e2, e3);
                }
            } else {
                const int thr = w * 16 + ln;            // q local in 64-block
                #pragma unroll
                for (int st = 0; st < 4; ++st) {
                    float e[4];
                    #pragma unroll
                    for (int r = 0; r < 4; ++r) {
                        const int key = st * 16 + quad * 4 + r;
                        e[r] = (key > thr) ? 0.0f : exp2f(fmaf(s[st][r], K1, -K2));
                    }
                    lsum += (e[0] + e[1]) + (e[2] + e[3]);
                    pk[2 * st]     = pack2_bf16(e[0], e[1]);
                    pk[2 * st + 1] = pack2_bf16(e[2], e[3]);
                }
            }

            union { unsigned int u[4]; bf16x8 v; } a0, a1;
            a0.u[0] = pk[0]; a0.u[1] = pk[1]; a0.u[2] = pk[2]; a0.u[3] = pk[3];
            a1.u[0] = pk[4]; a1.u[1] = pk[5]; a1.u[2] = pk[6]; a1.u[3] = pk[7];

            __builtin_amdgcn_s_setprio(1);
            #pragma unroll
            for (int t = 0; t < 4; ++t) {
                o[t] = __builtin_amdgcn_mfma_f32_16x16x32_bf16(
                           a0.v, *(const bf16x8*)&Vs[cb][t * 16 + ln][quad * 8], o[t], 0, 0, 0);
                o[t] = __builtin_amdgcn_mfma_f32_16x16x32_bf16(
                           a1.v, *(const bf16x8*)&Vs[cb][t * 16 + ln][32 + quad * 8], o[t], 0, 0, 0);
            }
            __builtin_amdgcn_s_setprio(0);
        }

        float ls = lsum;
        ls += __shfl_xor(ls, 16);
        ls += __shfl_xor(ls, 32);
        #pragma unroll
        for (int r = 0; r < 4; ++r) {
            const float inv = 1.0f / __shfl(ls, quad * 4 + r);
            size_t obase = (size_t)(b * T_SEQ + qr0 + quad * 4 + r) * DIMC + h * HDIM;
            #pragma unroll
            for (int t = 0; t < 4; ++t)
                O[obase + t * 16 + ln] = f2bf(o[t][r] * inv);
        }

        // phase boundary: next phase's first ds_writes must not race
        // this phase's last ds_reads on slow waves.
        __syncthreads();
    }
}

// ===========================================================================
extern "C" void kernel_launch(void* const* d_in, const int* in_sizes, int n_in,
                              void* d_out, int out_size, void* d_ws, size_t ws_size,
                              hipStream_t stream) {
    const float* x  = (const float*)d_in[0];
    const float* wq = (const float*)d_in[1];
    const float* wk = (const float*)d_in[2];
    const float* wv = (const float*)d_in[3];
    const float* wo = (const float*)d_in[4];
    float* out = (float*)d_out;

    char* ws = (char*)d_ws;
    constexpr size_t MB = 1024 * 1024;
    u16* Qb  = (u16*)(ws);             // 16 MB [4096][2048]
    u16* Kb  = (u16*)(ws + 16 * MB);   //  4 MB [4096][512]
    u16* Vb  = (u16*)(ws + 20 * MB);   //  4 MB [4096][512]
    u16* Vtb = (u16*)(ws + 24 * MB);   //  4 MB [2][512][2048]
    u16* AOb = (u16*)(ws + 28 * MB);   // 16 MB [4096][2048]  (aliases xb)
    u16* xb  = AOb;                    // x dead before attn writes AOb
    u16* wqb = (u16*)(ws + 44 * MB);   //  8 MB
    u16* wkb = (u16*)(ws + 52 * MB);   //  2 MB
    u16* wvb = (u16*)(ws + 54 * MB);   //  2 MB
    u16* wob = (u16*)(ws + 56 * MB);   //  8 MB
    const int M = BATCH * T_SEQ;       // 4096

    hipLaunchKernelGGL(cvt5, dim3(2048), dim3(256), 0, stream,
                       x, wq, wk, wv, wo, xb, wqb, wkb, wvb, wob);
    hipLaunchKernelGGL(qkv_gemm, dim3(24, M / 128), dim3(256), 0, stream,
                       xb, wqb, wkb, wvb, Qb, Kb, Vb);
    hipLaunchKernelGGL(transpose_v, dim3(KVDIM / 32, M / 32), dim3(256), 0, stream, Vb, Vtb);
    hipLaunchKernelGGL(attn, dim3(16, NHEAD, BATCH), dim3(256), 0, stream,
                       Qb, Kb, Vtb, AOb);
    hipLaunchKernelGGL(gemm_out, dim3(DIMC / 128, M / 128), dim3(256), 0, stream,
                       AOb, wob, out);
}

// Round 9
// 288.159 us; speedup vs baseline: 1.2646x; 1.0756x over previous
//
#include <hip/hip_runtime.h>

// Attention_6219112645023 — fp32 in / fp32 out, bf16 internal compute (MFMA).
// B=2, T=2048, DIM=2048, NH=32, NKV=8, HD=64. Causal GQA + RoPE + projections.
// Pipeline: cvt5 -> qkv_gemm -> transpose(V) -> flash attn -> O gemm.
// R8/R9: attn — swapped QK^T + slot permutation + reg pipeline + setprio.
// R11: GEMM 128x128/BK=64 4-wave DBUF, XOR swizzle (conflicts=0).
// R13: counted vmcnt (never drain in loop); attn K/V dbuf, 1 barrier/kt. BEST.
// R14 lesson: B global->reg direct = 64B-segment L2 thrash, -36%. REVERTED.
// R15 lesson: splitting prefetch mid-tile halves latency-hiding distance,
//   -18%. REVERTED (all 8 glds issued at tile top, full tile ahead).
// R16: 2-D L2-aware XCD regions. Old swizzle gave each XCD ALL W col-tiles
// (12 MB streamed through 4 MB L2 -> 96 MB HBM re-fetch, 900-cyc glds).
// New: qkv XCD region = 16 rows x 6 cols (W 3 MB L2-resident, col-fast
// order keeps A panel hot); gemm_out = 16 rows x 4 cols (W 2 MB resident).
// Index-only change vs R13.

typedef unsigned short u16;
typedef __attribute__((ext_vector_type(8))) short bf16x8;  // 8 bf16 in 4 VGPRs
typedef __attribute__((ext_vector_type(4))) float f32x4;
typedef __attribute__((ext_vector_type(4))) unsigned short u16x4;

constexpr int T_SEQ = 2048;
constexpr int DIMC  = 2048;
constexpr int NHEAD = 32;
constexpr int HDIM  = 64;
constexpr int KVDIM = 512;   // NKV * HDIM
constexpr int BATCH = 2;

__device__ __forceinline__ u16 f2bf(float f) {
    union { float f; unsigned int i; } v; v.f = f;
    unsigned int r = v.i + 0x7FFFu + ((v.i >> 16) & 1u);   // RNE
    return (u16)(r >> 16);
}

// pack two f32 -> (bf16 lo = e0, bf16 hi = e1), truncating (P in [0,1]).
__device__ __forceinline__ unsigned int pack2_bf16(float e0, float e1) {
    return __builtin_amdgcn_perm(__float_as_uint(e1), __float_as_uint(e0),
                                 0x07060302u);
}

typedef __attribute__((address_space(1))) unsigned int as1_uint;
typedef __attribute__((address_space(3))) unsigned int as3_uint;
__device__ __forceinline__ void glds16(const u16* g, u16* l) {
    // async global->LDS, 16B/lane; LDS dest = wave-uniform base + lane*16
    __builtin_amdgcn_global_load_lds((as1_uint*)(u16*)g, (as3_uint*)l, 16, 0, 0);
}

// ===========================================================================
// Fused fp32->bf16 convert of all 5 inputs (one launch).
// ===========================================================================
__global__ __launch_bounds__(256) void cvt5(const float* __restrict__ x,
                                            const float* __restrict__ wq,
                                            const float* __restrict__ wk,
                                            const float* __restrict__ wv,
                                            const float* __restrict__ wo,
                                            u16* __restrict__ xb,  u16* __restrict__ wqb,
                                            u16* __restrict__ wkb, u16* __restrict__ wvb,
                                            u16* __restrict__ wob) {
    constexpr int E0 = BATCH * T_SEQ * DIMC;          // 8388608
    constexpr int E1 = E0 + DIMC * DIMC;              // +4194304
    constexpr int E2 = E1 + KVDIM * DIMC;             // +1048576
    constexpr int E3 = E2 + KVDIM * DIMC;             // +1048576
    constexpr int E4 = E3 + DIMC * DIMC;              // 18874368 total
    for (int i = (blockIdx.x * 256 + threadIdx.x) * 4; i < E4; i += gridDim.x * 1024) {
        const float* s; u16* d; int off;
        if (i < E0)      { s = x;  d = xb;  off = 0;  }
        else if (i < E1) { s = wq; d = wqb; off = E0; }
        else if (i < E2) { s = wk; d = wkb; off = E1; }
        else if (i < E3) { s = wv; d = wvb; off = E2; }
        else             { s = wo; d = wob; off = E3; }
        f32x4 v = *(const f32x4*)(s + (i - off));
        u16x4 o;
        #pragma unroll
        for (int e = 0; e < 4; ++e) o[e] = f2bf(v[e]);
        *(u16x4*)(d + (i - off)) = o;
    }
}

// ===========================================================================
// DBUF GEMM core (R13 schedule): C = A[M][K] . W[N][K]^T, 128x128 tile,
// BK=64, 256 threads (4 waves 2x2; per-wave 64x64 = acc[4][4]).
// LDS: 2 bufs x (A 128x64 + B 128x64) = 64 KiB -> 2 blocks/CU.
// Swizzle (conflicts=0 proven): logical (row,col) at LDS elem
//   row*64 + (col ^ ((row&7)*8)); glds SOURCE col pre-swizzled (linear dest).
// Per K-tile: s_barrier (cb^1 reads retired) -> issue ALL 8 glds t+1 ->
// vmcnt(8) (t's 8 done, t+1's 8 FLYING a full tile ahead) -> s_barrier ->
// 16 ds_read_b128 + 32 MFMA. Never drains to 0 in the loop.
// ===========================================================================
template <bool OUTF32>
__device__ __forceinline__ void dgemm_core(const u16* __restrict__ A,
                                           const u16* __restrict__ W,
                                           void* __restrict__ Cv,
                                           int rowBase, int colBase,
                                           int N, int K, bool rope) {
    __shared__ __align__(16) u16 Ash[2][128 * 64];   // 32 KiB
    __shared__ __align__(16) u16 Bsh[2][128 * 64];   // 32 KiB

    const int tid  = threadIdx.x;
    const int lane = tid & 63;
    const int w    = tid >> 6;           // 0..3
    const int quad = lane >> 4;
    const int ln   = lane & 15;
    const int wm   = (w >> 1) * 64;
    const int wn   = (w & 1) * 64;

    const int sr = lane >> 3;            // 0..7
    const int sc = 8 * ((lane & 7) ^ sr);
    const u16* aS = A + (size_t)(rowBase + w * 8 + sr) * K + sc;
    const u16* bS = W + (size_t)(colBase + w * 8 + sr) * K + sc;

    f32x4 acc[4][4] = {};
    const int NT = K / 64;
    const int swz = (ln & 7) * 8;

    // prologue: stage tile 0 -> buf 0 (8 glds/thread)
    #pragma unroll
    for (int r = 0; r < 4; ++r) {
        glds16(aS + (size_t)(r * 32) * K, &Ash[0][(w + 4 * r) * 512]);
        glds16(bS + (size_t)(r * 32) * K, &Bsh[0][(w + 4 * r) * 512]);
    }

    for (int t = 0; t < NT; ++t) {
        const int cb = t & 1;
        __builtin_amdgcn_s_barrier();          // reads of buf cb^1 complete
        __builtin_amdgcn_sched_barrier(0);

        if (t + 1 < NT) {
            const size_t ko = (size_t)(t + 1) * 64;
            u16* An = &Ash[cb ^ 1][0];
            u16* Bn = &Bsh[cb ^ 1][0];
            #pragma unroll
            for (int r = 0; r < 4; ++r) {
                glds16(aS + ko + (size_t)(r * 32) * K, An + (w + 4 * r) * 512);
                glds16(bS + ko + (size_t)(r * 32) * K, Bn + (w + 4 * r) * 512);
            }
            __builtin_amdgcn_sched_barrier(0);
            __asm__ __volatile__("s_waitcnt vmcnt(8)" ::: "memory");  // t done, t+1 flying
        } else {
            __asm__ __volatile__("s_waitcnt vmcnt(0)" ::: "memory");  // epilogue drain
        }
        __builtin_amdgcn_sched_barrier(0);
        __builtin_amdgcn_s_barrier();          // tile t published

        const u16* Ap = &Ash[cb][0];
        const u16* Bp = &Bsh[cb][0];
        #pragma unroll
        for (int q2 = 0; q2 < 2; ++q2) {
            bf16x8 bwf[4];
            #pragma unroll
            for (int n = 0; n < 4; ++n)
                bwf[n] = *(const bf16x8*)(Bp + (wn + n * 16 + ln) * 64
                                             + ((q2 * 32 + quad * 8) ^ swz));
            __builtin_amdgcn_s_setprio(1);
            #pragma unroll
            for (int m = 0; m < 4; ++m) {
                bf16x8 af = *(const bf16x8*)(Ap + (wm + m * 16 + ln) * 64
                                                + ((q2 * 32 + quad * 8) ^ swz));
                #pragma unroll
                for (int n = 0; n < 4; ++n)
                    acc[m][n] = __builtin_amdgcn_mfma_f32_16x16x32_bf16(af, bwf[n], acc[m][n], 0, 0, 0);
            }
            __builtin_amdgcn_s_setprio(0);
        }
    }

    if (rope) {
        // head-local d = j*16+ln; pairs (d, d+32) -> (acc[i][j], acc[i][j+2]).
        #pragma unroll
        for (int j = 0; j < 2; ++j) {
            const int d = j * 16 + ln;
            const float invrev = exp2f(-(float)d * (13.287712379549449f / 32.0f))
                                 * 0.15915494309189535f;   // /2pi
            #pragma unroll
            for (int i = 0; i < 4; ++i) {
                #pragma unroll
                for (int r = 0; r < 4; ++r) {
                    const int t = (rowBase + wm + i * 16 + quad * 4 + r) & (T_SEQ - 1);
                    float rev = (float)t * invrev;
                    float fr = rev - floorf(rev);
                    float sn = __builtin_amdgcn_sinf(fr);
                    float cs = __builtin_amdgcn_cosf(fr);
                    float a0 = acc[i][j][r], a2 = acc[i][j + 2][r];
                    acc[i][j][r]     = a0 * cs - a2 * sn;
                    acc[i][j + 2][r] = a2 * cs + a0 * sn;
                }
            }
        }
    }

    #pragma unroll
    for (int i = 0; i < 4; ++i) {
        int mrow = rowBase + wm + i * 16 + quad * 4;
        #pragma unroll
        for (int j = 0; j < 4; ++j) {
            int n = colBase + wn + j * 16 + ln;
            #pragma unroll
            for (int r = 0; r < 4; ++r) {
                if constexpr (OUTF32)
                    ((float*)Cv)[(size_t)(mrow + r) * N + n] = acc[i][j][r];
                else
                    ((u16*)Cv)[(size_t)(mrow + r) * N + n] = f2bf(acc[i][j][r]);
            }
        }
    }
}

// Fused QKV: 24 col-tiles (Q 16 | K 4 | V 4) x 32 row-tiles = 768 blocks.
// R16 XCD region: each XCD owns 16 rows x 6 cols (96 blocks).
//   xcd = flat&7 -> row-group = xcd>>2 (16 rows), col-group = xcd&3 (6 cols).
//   Within XCD col-fast: consecutive blocks share the A row-panel; the 6-col
//   W slab (3 MB) stays L2-resident across rows. Bijective (8*96 = 768).
__global__ __launch_bounds__(256, 2) void qkv_gemm(const u16* __restrict__ xb,
                                                   const u16* __restrict__ wqb,
                                                   const u16* __restrict__ wkb,
                                                   const u16* __restrict__ wvb,
                                                   u16* __restrict__ Qb,
                                                   u16* __restrict__ Kb,
                                                   u16* __restrict__ Vb) {
    const int flat = blockIdx.y * 24 + blockIdx.x;
    const int xcd  = flat & 7;
    const int idx  = flat >> 3;          // 0..95
    const int row  = (xcd >> 2) * 16 + idx / 6;
    const int ct   = (xcd & 3) * 6 + idx % 6;
    const int rowBase = row * 128;

    const u16* W; u16* C; int colBase, N; bool rope;
    if (ct < 16)      { W = wqb; C = Qb; colBase = ct * 128;        N = DIMC;  rope = true; }
    else if (ct < 20) { W = wkb; C = Kb; colBase = (ct - 16) * 128; N = KVDIM; rope = true; }
    else              { W = wvb; C = Vb; colBase = (ct - 20) * 128; N = KVDIM; rope = false; }
    dgemm_core<false>(xb, W, C, rowBase, colBase, N, DIMC, rope);
}

// O-projection: 16 col-tiles x 32 row-tiles = 512 blocks.
// R16 XCD region: 16 rows x 4 cols per XCD (W slab 2 MB L2-resident).
__global__ __launch_bounds__(256, 2) void gemm_out(const u16* __restrict__ A,
                                                   const u16* __restrict__ W,
                                                   float* __restrict__ C) {
    const int flat = blockIdx.y * 16 + blockIdx.x;
    const int xcd  = flat & 7;
    const int idx  = flat >> 3;          // 0..63
    const int row  = (xcd >> 2) * 16 + (idx >> 2);
    const int col  = (xcd & 3) * 4 + (idx & 3);
    dgemm_core<true>(A, W, C, row * 128, col * 128, DIMC, DIMC, false);
}

// ===========================================================================
// V [B*T][KVDIM] -> Vt [B][KVDIM][T]
// ===========================================================================
__global__ __launch_bounds__(256) void transpose_v(const u16* __restrict__ V,
                                                   u16* __restrict__ Vt) {
    __shared__ __align__(16) u16 tile[32][33];
    const int x = threadIdx.x & 31;
    const int y = threadIdx.x >> 5;
    const int tok0 = blockIdx.y * 32;
    const int c0   = blockIdx.x * 32;
    #pragma unroll
    for (int yy = 0; yy < 32; yy += 8)
        tile[y + yy][x] = V[(size_t)(tok0 + y + yy) * KVDIM + c0 + x];
    __syncthreads();
    const int b  = tok0 >> 11;
    const int t0 = tok0 & (T_SEQ - 1);
    #pragma unroll
    for (int yy = 0; yy < 32; yy += 8)
        Vt[(size_t)(b * KVDIM + c0 + y + yy) * T_SEQ + t0 + x] = tile[x][y + yy];
}

// ===========================================================================
// Flash attention. grid = (16, NH, B), block = 256 (4 waves).
// R8: swapped QK^T (D[key][q]) + key->slot permutation
//   slot(k) = 32*(k>>5) + 8*((k>>2)&3) + 4*((k>>4)&1) + (k&3)
// R9: T14 async-STAGE reg pipeline + T5 setprio.
// R13: K/V double-buffered (36 KB) -> ONE raw barrier per kt.
// ===========================================================================
__global__ __launch_bounds__(256) void attn(const u16* __restrict__ Q,
                                            const u16* __restrict__ Kx,
                                            const u16* __restrict__ Vt,
                                            u16* __restrict__ O) {
    __shared__ __align__(16) u16 Ks[2][64][72];    // [buf][key][dim]
    __shared__ __align__(16) u16 Vs[2][64][72];    // [buf][dim][slot]

    const int tid  = threadIdx.x;
    const int lane = tid & 63;
    const int w    = tid >> 6;
    const int quad = lane >> 4;
    const int ln   = lane & 15;
    const int h    = blockIdx.y;
    const int b    = blockIdx.z;
    const int kvh  = h >> 2;

    const int srow = tid >> 2;           // 0..63
    const int c    = tid & 3;
    const int scol = c * 16;             // token group base (16 tokens)
    const int vsb  = 32 * (c >> 1) + 4 * (c & 1);
    const u16* kbase = Kx + (size_t)(b * T_SEQ + srow) * KVDIM + kvh * HDIM + scol;
    const u16* vbase = Vt + (size_t)(b * KVDIM + kvh * HDIM + srow) * T_SEQ;

    const float K1 = 0.125f * 1.4426950408889634f;   // scale * log2(e)
    const float K2 = 8.0f * 1.4426950408889634f;     // M0 * log2(e)

    #pragma unroll
    for (int phase = 0; phase < 2; ++phase) {
        const int qt = phase ? (31 - (int)blockIdx.x) : (int)blockIdx.x;
        const int qr0 = qt * 64 + w * 16;

        const u16* qp = Q + (size_t)(b * T_SEQ + qr0 + ln) * DIMC + h * HDIM + quad * 8;
        const bf16x8 bq0 = *(const bf16x8*)qp;        // B-operand: col = q = ln
        const bf16x8 bq1 = *(const bf16x8*)(qp + 32);

        f32x4 o[4] = {};
        float lsum = 0.0f;

        // pipeline prologue: tile-0 staging loads into registers
        bf16x8 kra = *(const bf16x8*)kbase;
        bf16x8 krb = *(const bf16x8*)(kbase + 8);
        bf16x8 vra = *(const bf16x8*)(vbase + scol);
        bf16x8 vrb = *(const bf16x8*)(vbase + scol + 8);

        for (int kt = 0; kt <= qt; ++kt) {
            const int cb = kt & 1;

            *(bf16x8*)&Ks[cb][srow][scol]     = kra;
            *(bf16x8*)&Ks[cb][srow][scol + 8] = krb;
            {   // V staging, slot-permuted: 4x ds_write_b64
                union { bf16x8 v; u16x4 h4[2]; } ua, ub;
                ua.v = vra; ub.v = vrb;
                *(u16x4*)&Vs[cb][srow][vsb]      = ua.h4[0];
                *(u16x4*)&Vs[cb][srow][vsb + 8]  = ua.h4[1];
                *(u16x4*)&Vs[cb][srow][vsb + 16] = ub.h4[0];
                *(u16x4*)&Vs[cb][srow][vsb + 24] = ub.h4[1];
            }

            // prefetch tile kt+1 into regs — flies under this tile's compute
            if (kt < qt) {
                const size_t ko = (size_t)(kt + 1) * 64;
                kra = *(const bf16x8*)(kbase + ko * KVDIM);
                krb = *(const bf16x8*)(kbase + ko * KVDIM + 8);
                vra = *(const bf16x8*)(vbase + ko + scol);
                vrb = *(const bf16x8*)(vbase + ko + scol + 8);
            }

            // own LDS writes (and prior reads) drained, then ONE raw barrier
            __asm__ __volatile__("s_waitcnt lgkmcnt(0)" ::: "memory");
            __builtin_amdgcn_s_barrier();

            f32x4 s[4];
            __builtin_amdgcn_s_setprio(1);
            #pragma unroll
            for (int st = 0; st < 4; ++st) {
                f32x4 z = {};
                s[st] = __builtin_amdgcn_mfma_f32_16x16x32_bf16(
                            *(const bf16x8*)&Ks[cb][st * 16 + ln][quad * 8], bq0, z, 0, 0, 0);
                s[st] = __builtin_amdgcn_mfma_f32_16x16x32_bf16(
                            *(const bf16x8*)&Ks[cb][st * 16 + ln][32 + quad * 8], bq1, s[st], 0, 0, 0);
            }
            __builtin_amdgcn_s_setprio(0);

            unsigned int pk[8];
            if (kt != qt) {
                #pragma unroll
                for (int st = 0; st < 4; ++st) {
                    float e0 = exp2f(fmaf(s[st][0], K1, -K2));
                    float e1 = exp2f(fmaf(s[st][1], K1, -K2));
                    float e2 = exp2f(fmaf(s[st][2], K1, -K2));
                    float e3 = exp2f(fmaf(s[st][3], K1, -K2));
                    lsum += (e0 + e1) + (e2 + e3);
                    pk[2 * st]     = pack2_bf16(e0, e1);
                    pk[2 * st + 1] = pack2_bf16(e2, e3);
                }
            } else {
                const int thr = w * 16 + ln;            // q local in 64-block
                #pragma unroll
                for (int st = 0; st < 4; ++st) {
                    float e[4];
                    #pragma unroll
                    for (int r = 0; r < 4; ++r) {
                        const int key = st * 16 + quad * 4 + r;
                        e[r] = (key > thr) ? 0.0f : exp2f(fmaf(s[st][r], K1, -K2));
                    }
                    lsum += (e[0] + e[1]) + (e[2] + e[3]);
                    pk[2 * st]     = pack2_bf16(e[0], e[1]);
                    pk[2 * st + 1] = pack2_bf16(e[2], e[3]);
                }
            }

            union { unsigned int u[4]; bf16x8 v; } a0, a1;
            a0.u[0] = pk[0]; a0.u[1] = pk[1]; a0.u[2] = pk[2]; a0.u[3] = pk[3];
            a1.u[0] = pk[4]; a1.u[1] = pk[5]; a1.u[2] = pk[6]; a1.u[3] = pk[7];

            __builtin_amdgcn_s_setprio(1);
            #pragma unroll
            for (int t = 0; t < 4; ++t) {
                o[t] = __builtin_amdgcn_mfma_f32_16x16x32_bf16(
                           a0.v, *(const bf16x8*)&Vs[cb][t * 16 + ln][quad * 8], o[t], 0, 0, 0);
                o[t] = __builtin_amdgcn_mfma_f32_16x16x32_bf16(
                           a1.v, *(const bf16x8*)&Vs[cb][t * 16 + ln][32 + quad * 8], o[t], 0, 0, 0);
            }
            __builtin_amdgcn_s_setprio(0);
        }

        float ls = lsum;
        ls += __shfl_xor(ls, 16);
        ls += __shfl_xor(ls, 32);
        #pragma unroll
        for (int r = 0; r < 4; ++r) {
            const float inv = 1.0f / __shfl(ls, quad * 4 + r);
            size_t obase = (size_t)(b * T_SEQ + qr0 + quad * 4 + r) * DIMC + h * HDIM;
            #pragma unroll
            for (int t = 0; t < 4; ++t)
                O[obase + t * 16 + ln] = f2bf(o[t][r] * inv);
        }

        // phase boundary: next phase's first ds_writes must not race
        // this phase's last ds_reads on slow waves.
        __syncthreads();
    }
}

// ===========================================================================
extern "C" void kernel_launch(void* const* d_in, const int* in_sizes, int n_in,
                              void* d_out, int out_size, void* d_ws, size_t ws_size,
                              hipStream_t stream) {
    const float* x  = (const float*)d_in[0];
    const float* wq = (const float*)d_in[1];
    const float* wk = (const float*)d_in[2];
    const float* wv = (const float*)d_in[3];
    const float* wo = (const float*)d_in[4];
    float* out = (float*)d_out;

    char* ws = (char*)d_ws;
    constexpr size_t MB = 1024 * 1024;
    u16* Qb  = (u16*)(ws);             // 16 MB [4096][2048]
    u16* Kb  = (u16*)(ws + 16 * MB);   //  4 MB [4096][512]
    u16* Vb  = (u16*)(ws + 20 * MB);   //  4 MB [4096][512]
    u16* Vtb = (u16*)(ws + 24 * MB);   //  4 MB [2][512][2048]
    u16* AOb = (u16*)(ws + 28 * MB);   // 16 MB [4096][2048]  (aliases xb)
    u16* xb  = AOb;                    // x dead before attn writes AOb
    u16* wqb = (u16*)(ws + 44 * MB);   //  8 MB
    u16* wkb = (u16*)(ws + 52 * MB);   //  2 MB
    u16* wvb = (u16*)(ws + 54 * MB);   //  2 MB
    u16* wob = (u16*)(ws + 56 * MB);   //  8 MB
    const int M = BATCH * T_SEQ;       // 4096

    hipLaunchKernelGGL(cvt5, dim3(2048), dim3(256), 0, stream,
                       x, wq, wk, wv, wo, xb, wqb, wkb, wvb, wob);
    hipLaunchKernelGGL(qkv_gemm, dim3(24, M / 128), dim3(256), 0, stream,
                       xb, wqb, wkb, wvb, Qb, Kb, Vb);
    hipLaunchKernelGGL(transpose_v, dim3(KVDIM / 32, M / 32), dim3(256), 0, stream, Vb, Vtb);
    hipLaunchKernelGGL(attn, dim3(16, NHEAD, BATCH), dim3(256), 0, stream,
                       Qb, Kb, Vtb, AOb);
    hipLaunchKernelGGL(gemm_out, dim3(DIMC / 128, M / 128), dim3(256), 0, stream,
                       AOb, wob, out);
}